// Round 7
// baseline (278.778 us; speedup 1.0000x reference)
//
#include <hip/hip_runtime.h>

// PointTransformerLayer fused kernel for MI355X (gfx950) — round 5 design
// (second resubmit; rounds 5 and 6 both failed on GPU acquisition, not kernel).
// Changes vs r4 (158us main, 70us aux, occupancy 42%, all pipes <25% => stall-bound):
//  * main split by j-half: one block per (bt, i, half of 64 j). LDS 16KB/block,
//    persistent regs ~24/lane => ~2x resident blocks/CU to hide barrier latency.
//    Partial softmax sums (pd,pn) -> ws; tiny combine kernel divides.
//  * aux qkv path rewritten: 128 blocks, x staged in LDS, weight row in VGPRs.
// Weights hi/lo bf16 (2 MFMA/product), activations single bf16 (absmax 0.016 in r4).
// ws: qkv@0 (3145728), fW1@3145728 (12288), fW2@3158016 (16384),
//     fA1@3174400 (65536), fA2@3239936 (65536), part@3305472 (4194304) end ~7.5MB.

typedef short short8 __attribute__((ext_vector_type(8)));
typedef float f32x4 __attribute__((ext_vector_type(4)));
typedef float f32x16 __attribute__((ext_vector_type(16)));
typedef unsigned int u32x2 __attribute__((ext_vector_type(2)));

__device__ __forceinline__ unsigned short f2bf(float x) {
  union { float f; unsigned int u; } a; a.f = x;
  unsigned int r = a.u + 0x7fffu + ((a.u >> 16) & 1u);  // RNE
  return (unsigned short)(r >> 16);
}
__device__ __forceinline__ float bf2f(unsigned short h) {
  union { unsigned int u; float f; } a; a.u = ((unsigned int)h) << 16; return a.f;
}
__device__ __forceinline__ unsigned int pk2(float a, float b) {  // a->lo16, b->hi16
  unsigned int r;
  asm("v_cvt_pk_bf16_f32 %0, %1, %2" : "=v"(r) : "v"(a), "v"(b));
  return r;
}

// ---------------- aux: qkv GEMM + weight A-frag buffers ----------------
// A-frag (32x32x16): lane l holds A[row = mt*32 + (l&31)][k = kc*16 + (l>>5)*8 + e].
// linear: idx = ((mt*KC + kc)*64 + lane)*8 + e ; hi plane then lo plane (shorts).
__device__ __forceinline__ void fill_frag(unsigned short* dst, int plane,
    const float* src, int Ksrc, int KC, int idx) {
  int e = idx & 7;
  int lane = (idx >> 3) & 63;
  int kc = (idx >> 9) % KC;
  int mt = idx / (512 * KC);
  int row = mt * 32 + (lane & 31);
  int k = kc * 16 + ((lane >> 5) << 3) + e;
  float v = (k < Ksrc) ? src[row * Ksrc + k] : 0.0f;
  unsigned short hi = f2bf(v);
  unsigned short lo = f2bf(v - bf2f(hi));
  dst[idx] = hi;
  dst[plane + idx] = lo;
}

#define QKV_BLOCKS 128  // (bt 32) x (n-quarter 4)

__global__ void aux_kernel(const float* __restrict__ wqkv,
    const float* __restrict__ pw1, const float* __restrict__ pw2,
    const float* __restrict__ aw1, const float* __restrict__ aw2,
    const float* __restrict__ x,
    unsigned short* __restrict__ fW1, unsigned short* __restrict__ fW2,
    unsigned short* __restrict__ fA1, unsigned short* __restrict__ fA2,
    float* __restrict__ qkv) {
  int tid = threadIdx.x;
  if (blockIdx.x < QKV_BLOCKS) {  // ---- qkv: block = (bt, nq); 32 rows ----
    __shared__ float xs[32 * 64];
    int bt = blockIdx.x >> 2, nq = blockIdx.x & 3;
    const float* xb = x + (bt * 128 + nq * 32) * 64;
#pragma unroll
    for (int o = 0; o < 8; ++o) xs[tid + o * 256] = xb[tid + o * 256];
    __syncthreads();
    if (tid < 192) {
      const float* wr_g = wqkv + tid * 64;
      float wr[64];
#pragma unroll
      for (int k = 0; k < 64; ++k) wr[k] = wr_g[k];
      float* qb = qkv + (size_t)(bt * 128 + nq * 32) * 192 + tid;
      for (int n = 0; n < 32; ++n) {
        float acc = 0.f;
#pragma unroll
        for (int k = 0; k < 64; ++k) acc += xs[n * 64 + k] * wr[k];
        qb[n * 192] = acc;
      }
    }
    return;
  }
  int gid = (blockIdx.x - QKV_BLOCKS) * 256 + tid;
  if (gid < 3072) { fill_frag(fW1, 3072, pw1, 34, 3, gid); return; }    // [64][34->48]
  gid -= 3072;
  if (gid < 4096) { fill_frag(fW2, 4096, pw2, 64, 4, gid); return; }    // [64][64]
  gid -= 4096;
  if (gid < 16384) { fill_frag(fA1, 16384, aw1, 64, 4, gid); return; }  // [256][64]
  gid -= 16384;
  fill_frag(fA2, 16384, aw2, 256, 16, gid);                             // [64][256]
}

// ---------------- main fused kernel (per j-half) ----------------
// C/D layout 32x32: col = l&31, row = (reg&3) + 8*(reg>>2) + 4*(l>>5).
__device__ __forceinline__ f32x16 ld16(const float* p, int l) {
  f32x16 r;
#pragma unroll
  for (int q = 0; q < 4; ++q) {
    f32x4 v = *(const f32x4*)(p + 8 * q + ((l >> 5) << 2));
#pragma unroll
    for (int s = 0; s < 4; ++s) r[4 * q + s] = v[s];
  }
  return r;
}

// scatter C-tile (rows kcb*16..+31) into B-frag-linear LDS (2 j-tiles wide)
__device__ __forceinline__ void scat2(char* buf, int jt, int lc, int lh, int kcb,
                                      f32x16 a, bool relu) {
#pragma unroll
  for (int q = 0; q < 4; ++q) {
    float v0 = a[4*q], v1 = a[4*q+1], v2 = a[4*q+2], v3 = a[4*q+3];
    if (relu) {
      v0 = fmaxf(v0, 0.f); v1 = fmaxf(v1, 0.f);
      v2 = fmaxf(v2, 0.f); v3 = fmaxf(v3, 0.f);
    }
    u32x2 wv; wv[0] = pk2(v0, v1); wv[1] = pk2(v2, v3);
    int kc = kcb + (q >> 1);
    *(u32x2*)(buf + ((kc * 2 + jt) << 10) + (((q & 1) << 5) + lc) * 16 + lh * 8) = wv;
  }
}

#define MFMA32(acc, av, bv) \
  acc = __builtin_amdgcn_mfma_f32_32x32x16_bf16(av, bv, acc, 0, 0, 0)
#define MM2(accv, ahi, alo, bp) { short8 bb_ = *(bp); \
  MFMA32(accv, ahi, bb_); MFMA32(accv, alo, bb_); }

__global__ __launch_bounds__(256, 5) void main_kernel(
    const float* __restrict__ pos, const float* __restrict__ qkv,
    const unsigned short* __restrict__ fW1, const unsigned short* __restrict__ fW2,
    const unsigned short* __restrict__ fA1, const unsigned short* __restrict__ fA2,
    const float* __restrict__ pb1, const float* __restrict__ pb2,
    const float* __restrict__ ab1, const float* __restrict__ ab2,
    float* __restrict__ part) {
  __shared__ char bufA[8192];  // X1 (kc0..2) then U (kc0..3), frag-linear, 2 j-tiles
  __shared__ char bufB[8192];  // H1 then H2c; reused as f32 red[] in epilogue
  const int i = blockIdx.x >> 1, half = blockIdx.x & 1, bt = blockIdx.y;
  const int tid = threadIdx.x;
  const int w = tid >> 6, l = tid & 63;
  const int wm = w >> 1, wn = w & 1;
  const int lc = l & 31, lh = l >> 5;

  // ---- X1 frags: f = c*17+jj (34 real features, 48 padded); j = half*64 + l ----
#pragma unroll
  for (int it = 0; it < 12; ++it) {
    int f = w + 4 * it;        // uniform per wave per it
    float val = 0.f;
    if (f < 34) {
      int c = (f >= 17) ? 1 : 0;
      int jj = f - 17 * c;
      const float* ps = pos + (((bt * 17 + jj) * 3 + c) << 7);
      val = ps[i] - ps[half * 64 + l];
    }
    int kc = f >> 4, lane = ((f >> 3) & 1) * 32 + lc, jt = lh, e = f & 7;
    *(unsigned short*)(bufA + ((kc * 2 + jt) << 10) + lane * 16 + e * 2) = f2bf(val);
  }
  __syncthreads();

  // ---- G1: H1 = relu(W1 @ X1^T + b1) -> bufB frags (K=48); wave=(wm,jt=wn) ----
  {
    f32x16 acc = ld16(pb1 + wm * 32, l);
#pragma unroll
    for (int kc = 0; kc < 3; ++kc) {
      const unsigned short* ap = fW1 + ((wm * 3 + kc) * 64 + l) * 8;
      short8 ahi = *(const short8*)ap;
      short8 alo = *(const short8*)(ap + 3072);
      MM2(acc, ahi, alo, (const short8*)(bufA + ((kc * 2 + wn) << 10) + l * 16));
    }
    scat2(bufB, wn, lc, lh, 2 * wm, acc, true);
  }
  __syncthreads();

  // ---- G2 + E-stage: E = W2 @ H1^T + b2; U -> bufA frags; vp packed bf16 ----
  unsigned int vpk[8];
  {
    f32x16 e = ld16(pb2 + wm * 32, l);
#pragma unroll
    for (int kc = 0; kc < 4; ++kc) {
      const unsigned short* ap = fW2 + ((wm * 4 + kc) * 64 + l) * 8;
      short8 ahi = *(const short8*)ap;
      short8 alo = *(const short8*)(ap + 4096);
      MM2(e, ahi, alo, (const short8*)(bufB + ((kc * 2 + wn) << 10) + l * 16));
    }
    const float* qkv_bt = qkv + (size_t)(bt * 128) * 192;
    f32x16 qv = ld16(qkv_bt + i * 192 + wm * 32, l);
    const float* rp = qkv_bt + (half * 64 + wn * 32 + lc) * 192 + wm * 32;
    f32x16 kk = ld16(rp + 64, l), vv = ld16(rp + 128, l);
    f32x16 u;
#pragma unroll
    for (int r = 0; r < 16; ++r) u[r] = qv[r] - kk[r] + e[r];
#pragma unroll
    for (int s = 0; s < 8; ++s)
      vpk[s] = pk2(vv[2*s] + e[2*s], vv[2*s+1] + e[2*s+1]);
    scat2(bufA, wn, lc, lh, 2 * wm, u, false);
  }
  __syncthreads();

  // ---- G3/G4 over 4 h-chunks of 64; s = S^T[d][j] quadrant (wm, wn) ----
  f32x16 s = ld16(ab2 + wm * 32, l);
#pragma unroll 1
  for (int hc = 0; hc < 4; ++hc) {
    {  // G3: H2c = relu(A1c @ U^T + b1c); wave = (mt=wm, jt=wn)
      f32x16 h = ld16(ab1 + hc * 64 + wm * 32, l);
#pragma unroll
      for (int kc = 0; kc < 4; ++kc) {
        const unsigned short* ap = fA1 + (((hc * 2 + wm) * 4 + kc) * 64 + l) * 8;
        short8 ahi = *(const short8*)ap;
        short8 alo = *(const short8*)(ap + 16384);
        MM2(h, ahi, alo, (const short8*)(bufA + ((kc * 2 + wn) << 10) + l * 16));
      }
      scat2(bufB, wn, lc, lh, 2 * wm, h, true);
    }
    __syncthreads();
    {  // G4: S += A2c @ H2c^T
#pragma unroll
      for (int kc = 0; kc < 4; ++kc) {
        const unsigned short* ap = fA2 + ((wm * 16 + hc * 4 + kc) * 64 + l) * 8;
        short8 ahi = *(const short8*)ap;
        short8 alo = *(const short8*)(ap + 16384);
        MM2(s, ahi, alo, (const short8*)(bufB + ((kc * 2 + wn) << 10) + l * 16));
      }
    }
    __syncthreads();
  }

  // ---- epilogue: partial softmax sums over this block's 64 j ----
  float* red = (float*)bufB;  // [wn][pd 64 | pn 64] after cross-lane reduce
#pragma unroll
  for (int q = 0; q < 4; ++q) {
#pragma unroll
    for (int sp = 0; sp < 2; ++sp) {
      int r0 = 4 * q + 2 * sp;
      int pi = 2 * q + sp;
      float x0 = __expf(s[r0]), x1 = __expf(s[r0 + 1]);
      float v0 = __uint_as_float(vpk[pi] << 16);
      float v1 = __uint_as_float(vpk[pi] & 0xffff0000u);
      float pdA = x0, pnA = x0 * v0;
      float pdB = x1, pnB = x1 * v1;
#pragma unroll
      for (int m = 1; m <= 16; m <<= 1) {
        pdA += __shfl_xor(pdA, m); pnA += __shfl_xor(pnA, m);
        pdB += __shfl_xor(pdB, m); pnB += __shfl_xor(pnB, m);
      }
      if (lc == 0) {
        int dA = wm * 32 + (r0 & 3) + 8 * (r0 >> 2) + 4 * lh;
        red[wn * 128 + dA] = pdA;      red[wn * 128 + 64 + dA] = pnA;
        red[wn * 128 + dA + 1] = pdB;  red[wn * 128 + 64 + dA + 1] = pnB;
      }
    }
  }
  __syncthreads();
  if (tid < 128) {  // combine 2 j-tiles; write [pd 64 | pn 64] partial for this half
    float v = red[tid] + red[128 + tid];
    part[((size_t)(bt * 128 + i) * 2 + half) * 128 + tid] = v;
  }
}

// ---------------- combine: out = (pn0+pn1)/(pd0+pd1) ----------------
__global__ void combine_kernel(const float* __restrict__ part, float* __restrict__ out) {
  int gid = blockIdx.x * 256 + threadIdx.x;   // 262144 = 4096 bi * 64 d
  int bi = gid >> 6, d = gid & 63;
  const float* p = part + (size_t)bi * 256;
  float pd = p[d] + p[128 + d];
  float pn = p[64 + d] + p[192 + d];
  out[gid] = pn / pd;
}

extern "C" void kernel_launch(void* const* d_in, const int* in_sizes, int n_in,
                              void* d_out, int out_size, void* d_ws, size_t ws_size,
                              hipStream_t stream) {
  const float* x    = (const float*)d_in[0];
  const float* pos  = (const float*)d_in[1];
  const float* wqkv = (const float*)d_in[2];
  const float* pw1  = (const float*)d_in[3];
  const float* pb1  = (const float*)d_in[4];
  const float* pw2  = (const float*)d_in[5];
  const float* pb2  = (const float*)d_in[6];
  const float* aw1  = (const float*)d_in[7];
  const float* ab1  = (const float*)d_in[8];
  const float* aw2  = (const float*)d_in[9];
  const float* ab2  = (const float*)d_in[10];
  float* out = (float*)d_out;
  char* ws = (char*)d_ws;

  float* qkv = (float*)ws;                               // 3145728 B
  unsigned short* fW1 = (unsigned short*)(ws + 3145728); // 12288 B
  unsigned short* fW2 = (unsigned short*)(ws + 3158016); // 16384 B
  unsigned short* fA1 = (unsigned short*)(ws + 3174400); // 65536 B
  unsigned short* fA2 = (unsigned short*)(ws + 3239936); // 65536 B
  float* part = (float*)(ws + 3305472);                  // 4194304 B (end ~7.5MB)

  hipLaunchKernelGGL(aux_kernel, dim3(QKV_BLOCKS + 156), dim3(256), 0, stream,
                     wqkv, pw1, pw2, aw1, aw2, x, fW1, fW2, fA1, fA2, qkv);
  hipLaunchKernelGGL(main_kernel, dim3(256, 32), dim3(256), 0, stream,
                     pos, qkv, fW1, fW2, fA1, fA2, pb1, pb2, ab1, ab2, part);
  hipLaunchKernelGGL(combine_kernel, dim3(1024), dim3(256), 0, stream, part, out);
}

// Round 8
// 168.523 us; speedup vs baseline: 1.6542x; 1.6542x over previous
//
#include <hip/hip_runtime.h>

// PointTransformerLayer fused kernel for MI355X (gfx950) — round 8.
// vs r4/r7 (stall-bound: ~5-7K cycles stall per barrier phase, serial 8-deep
// MFMA chains + in-phase weight fetches):
//  * single-bf16 weights (1 MFMA/product): chain depth 8->4, weight bytes /2.
//    absmax predicted ~0.03 vs threshold 0.088 (r4 measured 0.0156).
//  * full-j blocks again (r7 j-split regressed: per-block overhead x2, +combine).
//  * weight frags prefetched into VGPRs ACROSS barriers (a2f held through G3).
//  * 2 kernels only; qkv at 512 blocks.
// ws: qkv@0 (3145728), fW1@3145728 (6144), fW2@3151872 (8192),
//     fA1@3160064 (32768), fA2@3192832 (32768); end 3225600 B.

typedef short short8 __attribute__((ext_vector_type(8)));
typedef float f32x4 __attribute__((ext_vector_type(4)));
typedef float f32x16 __attribute__((ext_vector_type(16)));
typedef unsigned int u32x2 __attribute__((ext_vector_type(2)));

__device__ __forceinline__ unsigned short f2bf(float x) {
  union { float f; unsigned int u; } a; a.f = x;
  unsigned int r = a.u + 0x7fffu + ((a.u >> 16) & 1u);  // RNE
  return (unsigned short)(r >> 16);
}
__device__ __forceinline__ unsigned int pk2(float a, float b) {  // a->lo16, b->hi16
  unsigned int r;
  asm("v_cvt_pk_bf16_f32 %0, %1, %2" : "=v"(r) : "v"(a), "v"(b));
  return r;
}

// ---------------- aux: qkv GEMM + single-plane weight A-frags ----------------
// A-frag (32x32x16): lane l holds A[row = mt*32 + (l&31)][k = kc*16 + (l>>5)*8 + e].
// linear: idx = ((mt*KC + kc)*64 + lane)*8 + e.
__device__ __forceinline__ void fill_frag(unsigned short* dst,
    const float* src, int Ksrc, int KC, int idx) {
  int e = idx & 7;
  int lane = (idx >> 3) & 63;
  int kc = (idx >> 9) % KC;
  int mt = idx / (512 * KC);
  int row = mt * 32 + (lane & 31);
  int k = kc * 16 + ((lane >> 5) << 3) + e;
  float v = (k < Ksrc) ? src[row * Ksrc + k] : 0.0f;
  dst[idx] = f2bf(v);
}

#define QKV_BLOCKS 512  // (bt 32) x (n-group 16), 8 rows each

__global__ void aux_kernel(const float* __restrict__ wqkv,
    const float* __restrict__ pw1, const float* __restrict__ pw2,
    const float* __restrict__ aw1, const float* __restrict__ aw2,
    const float* __restrict__ x,
    unsigned short* __restrict__ fW1, unsigned short* __restrict__ fW2,
    unsigned short* __restrict__ fA1, unsigned short* __restrict__ fA2,
    float* __restrict__ qkv) {
  int tid = threadIdx.x;
  if (blockIdx.x < QKV_BLOCKS) {  // ---- qkv: 8 rows of x per block ----
    __shared__ float xs[512];
    int bt = blockIdx.x >> 4, ng = blockIdx.x & 15;
    const float* xb = x + (bt * 128 + ng * 8) * 64;
    xs[tid] = xb[tid];
    xs[tid + 256] = xb[tid + 256];
    __syncthreads();
    if (tid < 192) {
      const float* wr_g = wqkv + tid * 64;
      float wr[64];
#pragma unroll
      for (int k = 0; k < 64; ++k) wr[k] = wr_g[k];
      float* qb = qkv + (size_t)(bt * 128 + ng * 8) * 192 + tid;
#pragma unroll
      for (int n = 0; n < 8; ++n) {
        float acc = 0.f;
#pragma unroll
        for (int k = 0; k < 64; ++k) acc += xs[n * 64 + k] * wr[k];
        qb[n * 192] = acc;
      }
    }
    return;
  }
  int gid = (blockIdx.x - QKV_BLOCKS) * 256 + tid;  // 39936 frag elems
  if (gid < 3072) { fill_frag(fW1, pw1, 34, 3, gid); return; }    // [64][34->48]
  gid -= 3072;
  if (gid < 4096) { fill_frag(fW2, pw2, 64, 4, gid); return; }    // [64][64]
  gid -= 4096;
  if (gid < 16384) { fill_frag(fA1, aw1, 64, 4, gid); return; }   // [256][64]
  gid -= 16384;
  fill_frag(fA2, aw2, 256, 16, gid);                              // [64][256]
}

// ---------------- main fused kernel ----------------
// C/D layout 32x32: col = l&31, row = (reg&3) + 8*(reg>>2) + 4*(l>>5).
__device__ __forceinline__ f32x16 ld16(const float* p, int l) {
  f32x16 r;
#pragma unroll
  for (int q = 0; q < 4; ++q) {
    f32x4 v = *(const f32x4*)(p + 8 * q + ((l >> 5) << 2));
#pragma unroll
    for (int s = 0; s < 4; ++s) r[4 * q + s] = v[s];
  }
  return r;
}

// scatter C-tile (rows kcb*16..+31) into B-frag-linear LDS (4 j-tiles wide)
__device__ __forceinline__ void scat(char* buf, int jt, int lc, int lh, int kcb,
                                     f32x16 a, bool relu) {
#pragma unroll
  for (int q = 0; q < 4; ++q) {
    float v0 = a[4*q], v1 = a[4*q+1], v2 = a[4*q+2], v3 = a[4*q+3];
    if (relu) {
      v0 = fmaxf(v0, 0.f); v1 = fmaxf(v1, 0.f);
      v2 = fmaxf(v2, 0.f); v3 = fmaxf(v3, 0.f);
    }
    u32x2 wv; wv[0] = pk2(v0, v1); wv[1] = pk2(v2, v3);
    int kc = kcb + (q >> 1);
    *(u32x2*)(buf + ((kc * 4 + jt) << 10) + (((q & 1) << 5) + lc) * 16 + lh * 8) = wv;
  }
}

#define MFMA32(acc, av, bv) \
  acc = __builtin_amdgcn_mfma_f32_32x32x16_bf16(av, bv, acc, 0, 0, 0)

__global__ __launch_bounds__(256, 4) void main_kernel(
    const float* __restrict__ pos, const float* __restrict__ qkv,
    const unsigned short* __restrict__ fW1, const unsigned short* __restrict__ fW2,
    const unsigned short* __restrict__ fA1, const unsigned short* __restrict__ fA2,
    const float* __restrict__ pb1, const float* __restrict__ pb2,
    const float* __restrict__ ab1, const float* __restrict__ ab2,
    float* __restrict__ out) {
  __shared__ char bufA[16384];  // X1 (kc0..2) then U (kc0..3), frag-linear
  __shared__ char bufB[16384];  // H1 then H2c; reused as f32 red[] in epilogue
  const int i = blockIdx.x, bt = blockIdx.y;
  const int tid = threadIdx.x;
  const int w = tid >> 6, l = tid & 63;
  const int wm = w >> 1, wn = w & 1;
  const int lc = l & 31, lh = l >> 5;

  // prefetch G1 + G2 weight frags (held in VGPRs across the X1/G1 barriers)
  short8 w1f[3], w2f[4];
#pragma unroll
  for (int kc = 0; kc < 3; ++kc)
    w1f[kc] = *(const short8*)(fW1 + ((wm * 3 + kc) * 64 + l) * 8);
#pragma unroll
  for (int kc = 0; kc < 4; ++kc)
    w2f[kc] = *(const short8*)(fW2 + ((wm * 4 + kc) * 64 + l) * 8);

  // ---- X1 frags: f = c*17+jj (34 real features, 48 with zero pad) ----
#pragma unroll
  for (int it = 0; it < 24; ++it) {
    int idx = tid + (it << 8);
    int f = idx >> 7, j = idx & 127;
    float val = 0.f;
    if (f < 34) {
      int c = (f >= 17) ? 1 : 0;
      int jj = f - 17 * c;
      const float* ps = pos + (((bt * 17 + jj) * 3 + c) << 7);
      val = ps[i] - ps[j];
    }
    int kc = f >> 4, lane = ((f >> 3) & 1) * 32 + (j & 31), jt = j >> 5, e = f & 7;
    *(unsigned short*)(bufA + ((kc * 4 + jt) << 10) + lane * 16 + e * 2) = f2bf(val);
  }
  __syncthreads();

  // ---- G1: H1 = relu(W1 @ X1^T + b1) -> bufB frags (K=48) ----
#pragma unroll
  for (int jr = 0; jr < 2; ++jr) {
    int jt = 2 * wn + jr;
    f32x16 acc = ld16(pb1 + wm * 32, l);
#pragma unroll
    for (int kc = 0; kc < 3; ++kc) {
      short8 b = *(const short8*)(bufA + ((kc * 4 + jt) << 10) + l * 16);
      MFMA32(acc, w1f[kc], b);
    }
    scat(bufB, jt, lc, lh, 2 * wm, acc, true);
  }
  __syncthreads();

  // ---- G2 + E-stage: E = W2 @ H1^T + b2; U -> bufA frags; vp packed bf16 ----
  unsigned int vpk0[8], vpk1[8];
  const float* qkv_bt = qkv + (size_t)(bt * 128) * 192;
  const float* qp = qkv_bt + i * 192 + wm * 32;
#pragma unroll
  for (int jr = 0; jr < 2; ++jr) {
    int jt = 2 * wn + jr;
    f32x16 e = ld16(pb2 + wm * 32, l);
#pragma unroll
    for (int kc = 0; kc < 4; ++kc) {
      short8 b = *(const short8*)(bufB + ((kc * 4 + jt) << 10) + l * 16);
      MFMA32(e, w2f[kc], b);
    }
    f32x16 qv = ld16(qp, l);
    const float* rp = qkv_bt + (jt * 32 + lc) * 192 + wm * 32;
    f32x16 kk = ld16(rp + 64, l), vv = ld16(rp + 128, l);
    f32x16 u;
#pragma unroll
    for (int r = 0; r < 16; ++r) u[r] = qv[r] - kk[r] + e[r];
#pragma unroll
    for (int s = 0; s < 8; ++s) {
      unsigned int p = pk2(vv[2*s] + e[2*s], vv[2*s+1] + e[2*s+1]);
      if (jr == 0) vpk0[s] = p; else vpk1[s] = p;
    }
    scat(bufA, jt, lc, lh, 2 * wm, u, false);
  }
  __syncthreads();

  // ---- G3/G4 over 4 h-chunks of 64; s0/s1 = S^T[d][j] for jt=2wn / 2wn+1 ----
  f32x16 s0 = ld16(ab2 + wm * 32, l), s1 = s0;
#pragma unroll 1
  for (int hc = 0; hc < 4; ++hc) {
    // prefetch this chunk's weight frags; a2f survives across G3 + barrier
    short8 a1f[4], a2f[4];
#pragma unroll
    for (int kc = 0; kc < 4; ++kc) {
      a1f[kc] = *(const short8*)(fA1 + (((hc * 2 + wm) * 4 + kc) * 64 + l) * 8);
      a2f[kc] = *(const short8*)(fA2 + ((wm * 16 + hc * 4 + kc) * 64 + l) * 8);
    }
#pragma unroll
    for (int jr = 0; jr < 2; ++jr) {  // G3: H2c = relu(A1c @ U^T + b1c)
      int jt = 2 * wn + jr;
      f32x16 h = ld16(ab1 + hc * 64 + wm * 32, l);
#pragma unroll
      for (int kc = 0; kc < 4; ++kc) {
        short8 b = *(const short8*)(bufA + ((kc * 4 + jt) << 10) + l * 16);
        MFMA32(h, a1f[kc], b);
      }
      scat(bufB, jt, lc, lh, 2 * wm, h, true);
    }
    __syncthreads();
    {  // G4: S += A2c @ H2c^T (a2f already resident)
#pragma unroll
      for (int kc = 0; kc < 4; ++kc) {
        short8 b = *(const short8*)(bufB + ((kc * 4 + 2 * wn) << 10) + l * 16);
        MFMA32(s0, a2f[kc], b);
      }
#pragma unroll
      for (int kc = 0; kc < 4; ++kc) {
        short8 b = *(const short8*)(bufB + ((kc * 4 + 2 * wn + 1) << 10) + l * 16);
        MFMA32(s1, a2f[kc], b);
      }
    }
    __syncthreads();
  }

  // ---- epilogue: softmax over j (no max-sub, exp-safe) + weighted vp sum ----
  float* red = (float*)bufA;  // pd[2][64] then pn[2][64]
#pragma unroll
  for (int q = 0; q < 4; ++q) {
#pragma unroll
    for (int sp = 0; sp < 2; ++sp) {
      int r0 = 4 * q + 2 * sp;
      int pi = 2 * q + sp;
      float x00 = __expf(s0[r0]),     x10 = __expf(s1[r0]);
      float x01 = __expf(s0[r0 + 1]), x11 = __expf(s1[r0 + 1]);
      float v00 = __uint_as_float(vpk0[pi] << 16);
      float v01 = __uint_as_float(vpk0[pi] & 0xffff0000u);
      float v10 = __uint_as_float(vpk1[pi] << 16);
      float v11 = __uint_as_float(vpk1[pi] & 0xffff0000u);
      float pdA = x00 + x10, pnA = x00 * v00 + x10 * v10;
      float pdB = x01 + x11, pnB = x01 * v01 + x11 * v11;
#pragma unroll
      for (int m = 1; m <= 16; m <<= 1) {
        pdA += __shfl_xor(pdA, m); pnA += __shfl_xor(pnA, m);
        pdB += __shfl_xor(pdB, m); pnB += __shfl_xor(pnB, m);
      }
      if (lc == 0) {
        int dA = wm * 32 + (r0 & 3) + 8 * (r0 >> 2) + 4 * lh;
        red[wn * 64 + dA] = pdA;       red[128 + wn * 64 + dA] = pnA;
        red[wn * 64 + dA + 1] = pdB;   red[128 + wn * 64 + dA + 1] = pnB;
      }
    }
  }
  __syncthreads();
  if (tid < 64) {
    float den = red[tid] + red[64 + tid];
    float num = red[128 + tid] + red[192 + tid];
    out[(bt * 128 + i) * 64 + tid] = num / den;
  }
}

extern "C" void kernel_launch(void* const* d_in, const int* in_sizes, int n_in,
                              void* d_out, int out_size, void* d_ws, size_t ws_size,
                              hipStream_t stream) {
  const float* x    = (const float*)d_in[0];
  const float* pos  = (const float*)d_in[1];
  const float* wqkv = (const float*)d_in[2];
  const float* pw1  = (const float*)d_in[3];
  const float* pb1  = (const float*)d_in[4];
  const float* pw2  = (const float*)d_in[5];
  const float* pb2  = (const float*)d_in[6];
  const float* aw1  = (const float*)d_in[7];
  const float* ab1  = (const float*)d_in[8];
  const float* aw2  = (const float*)d_in[9];
  const float* ab2  = (const float*)d_in[10];
  float* out = (float*)d_out;
  char* ws = (char*)d_ws;

  float* qkv = (float*)ws;                               // 3145728 B
  unsigned short* fW1 = (unsigned short*)(ws + 3145728); // 6144 B
  unsigned short* fW2 = (unsigned short*)(ws + 3151872); // 8192 B
  unsigned short* fA1 = (unsigned short*)(ws + 3160064); // 32768 B
  unsigned short* fA2 = (unsigned short*)(ws + 3192832); // 32768 B (end 3225600)

  hipLaunchKernelGGL(aux_kernel, dim3(QKV_BLOCKS + 156), dim3(256), 0, stream,
                     wqkv, pw1, pw2, aw1, aw2, x, fW1, fW2, fA1, fA2, qkv);
  hipLaunchKernelGGL(main_kernel, dim3(128, 32), dim3(256), 0, stream,
                     pos, qkv, fW1, fW2, fA1, fA2, pb1, pb2, ab1, ab2, out);
}